// Round 16
// baseline (502.626 us; speedup 1.0000x reference)
//
#include <hip/hip_runtime.h>
#include <hip/hip_bf16.h>

#define T_SEQ 1024
#define CHUNK 64
#define NCHUNK 16

__device__ __forceinline__ float fast_sigmoid(float x) {
    return 1.0f / (1.0f + __expf(-x));
}
__device__ __forceinline__ float fast_tanh(float x) {
    float e = __expf(2.0f * x);
    return 1.0f - 2.0f / (e + 1.0f);
}

// sum within each 4-lane quad via DPP quad_perm (pure VALU, no LDS)
__device__ __forceinline__ float quad_sum(float x) {
    int y1 = __builtin_amdgcn_mov_dpp(__float_as_int(x), 0xB1, 0xF, 0xF, true); // [1,0,3,2]
    float s1 = x + __int_as_float(y1);
    int y2 = __builtin_amdgcn_mov_dpp(__float_as_int(s1), 0x4E, 0xF, 0xF, true); // [2,3,0,1]
    return s1 + __int_as_float(y2);
}

// K1: precompute u-dependent parts of both RNN linears (+bias)
__global__ __launch_bounds__(256) void k_rnn_pre(
    const float* __restrict__ u,
    const float* __restrict__ i2h_w, const float* __restrict__ i2h_b,
    const float* __restrict__ h2o_w, const float* __restrict__ h2o_b,
    float* __restrict__ pre_i, float* __restrict__ pre_o) {
    int idx = blockIdx.x * 256 + threadIdx.x;   // 0..65535
    int k = idx >> 6, i = idx & 63;
    float a = i2h_b[i], b = h2o_b[i];
#pragma unroll
    for (int c = 0; c < 8; ++c) {
        float uv = u[k * 8 + c];
        a += uv * i2h_w[i * 72 + c];
        b += uv * h2o_w[i * 72 + c];
    }
    pre_i[idx] = a;
    pre_o[idx] = b;
}

// K3: RNN outputs, 4 rows per 256-thread block (hseq[k] = h BEFORE step k)
__global__ __launch_bounds__(256) void k_rnn_out(
    const float* __restrict__ h2o_w,
    const float* __restrict__ pre_o,
    const float* __restrict__ hseq,
    float* __restrict__ uout) {
    const int tid = threadIdx.x;
    const int sub = tid >> 6, i = tid & 63;
    const int k = blockIdx.x * 4 + sub;
    __shared__ float hk[4][64];
    hk[sub][i] = hseq[k * 64 + i];
    __syncthreads();
    float acc = pre_o[k * 64 + i];
    const float4* h4 = reinterpret_cast<const float4*>(hk[sub]);
#pragma unroll
    for (int v = 0; v < 16; ++v) {
        float4 hv = h4[v];
        acc += h2o_w[i * 72 + 8 + 4*v+0] * hv.x + h2o_w[i * 72 + 8 + 4*v+1] * hv.y
             + h2o_w[i * 72 + 8 + 4*v+2] * hv.z + h2o_w[i * 72 + 8 + 4*v+3] * hv.w;
    }
    uout[k * 64 + i] = fast_tanh(acc);
}

// ---- packed weight block layout (floats) ----
#define P_SW1 0       // xw1 padded rows of 68
#define P_SB1 1360
#define P_SW2 1380
#define P_SB2 1780
#define P_UW1 1800
#define P_UB1 3160
#define P_UW2 3180
#define P_UB2 3580
#define P_XW3 3600
#define P_XB3 4880
#define P_UW3 4944
#define P_UB3 6224
#define P_CWT 6288    // cwT[128][64]
#define P_CB  14480
#define P_TOT 14544   // 58176 bytes

__global__ __launch_bounds__(256) void k_repack(
    const float* __restrict__ xw1, const float* __restrict__ uw1,
    const float* __restrict__ xw2, const float* __restrict__ uw2,
    const float* __restrict__ xw3, const float* __restrict__ uw3,
    const float* __restrict__ cw,
    const float* __restrict__ xb1, const float* __restrict__ xb2,
    const float* __restrict__ ub1, const float* __restrict__ ub2,
    const float* __restrict__ xb3, const float* __restrict__ ub3,
    const float* __restrict__ cb, float* __restrict__ wp) {
    int i = blockIdx.x * 256 + threadIdx.x;
    if (i >= P_TOT) return;
    float v = 0.0f;
    if (i < 1360) {
        int o = i / 68, c = i - o * 68;
        if (c == 0) v = xw1[o * 65];
        else if (c >= 4) v = xw1[o * 65 + c - 3];
    } else if (i < 1380) v = xb1[i - 1360];
    else if (i < 1780) v = xw2[i - 1380];
    else if (i < 1800) v = xb2[i - 1780];
    else if (i < 3160) {
        int j = i - 1800; int o = j / 68, c = j - o * 68;
        if (c == 0) v = uw1[o * 65];
        else if (c >= 4) v = uw1[o * 65 + c - 3];
    } else if (i < 3180) v = ub1[i - 3160];
    else if (i < 3580) v = uw2[i - 3180];
    else if (i < 3600) v = ub2[i - 3580];
    else if (i < 4880) v = xw3[i - 3600];
    else if (i < 4944) v = xb3[i - 4880];
    else if (i < 6224) v = uw3[i - 4944];
    else if (i < 6288) v = ub3[i - 6224];
    else if (i < 14480) {
        int j = i - 6288; int row = j >> 6, s = j & 63;
        v = cw[s * 128 + row];
    }
    else v = cb[i - 14480];
    wp[i] = v;
}

// ---- MLP helpers (read LDS weight block) ----
template <int OW1, int OB1, int OW2, int OB2>
__device__ __forceinline__ void mlp20(const float* __restrict__ sm,
                                      float tval, const float4* z, float* h2) {
    float h1[20];
#pragma unroll 4
    for (int o = 0; o < 20; ++o) {
        const int ro = OW1 + o * 68;
        float a = sm[OB1 + o] + tval * sm[ro];
        const float4* wr = reinterpret_cast<const float4*>(&sm[ro + 4]);
#pragma unroll
        for (int v = 0; v < 16; ++v) {
            float4 w4 = wr[v];
            a += z[v].x * w4.x + z[v].y * w4.y + z[v].z * w4.z + z[v].w * w4.w;
        }
        h1[o] = fast_sigmoid(a);
    }
#pragma unroll 4
    for (int o = 0; o < 20; ++o) {
        float a = sm[OB2 + o];
        const float4* wr = reinterpret_cast<const float4*>(&sm[OW2 + o * 20]);
#pragma unroll
        for (int v = 0; v < 5; ++v) {
            float4 w4 = wr[v];
            a += h1[4*v+0]*w4.x + h1[4*v+1]*w4.y + h1[4*v+2]*w4.z + h1[4*v+3]*w4.w;
        }
        h2[o] = fast_sigmoid(a);
    }
}

template <int OW3, int OB3, int OCWT>
__device__ __forceinline__ void final64(const float* __restrict__ sm,
                                        const float* h2, float* oacc) {
#pragma unroll 2
    for (int o = 0; o < 64; ++o) {
        float a = sm[OB3 + o];
        const float4* wr = reinterpret_cast<const float4*>(&sm[OW3 + o * 20]);
#pragma unroll
        for (int v = 0; v < 5; ++v) {
            float4 w4 = wr[v];
            a += h2[4*v+0]*w4.x + h2[4*v+1]*w4.y + h2[4*v+2]*w4.z + h2[4*v+3]*w4.w;
        }
        float s = fast_sigmoid(a);
        const float4* cr = reinterpret_cast<const float4*>(&sm[OCWT + o * 64]);
#pragma unroll
        for (int v = 0; v < 16; ++v) {
            float4 c4 = cr[v];
            oacc[4*v+0] += s * c4.x; oacc[4*v+1] += s * c4.y;
            oacc[4*v+2] += s * c4.z; oacc[4*v+3] += s * c4.w;
        }
    }
}

// ---- K_MAIN ----
// block 0, wave 0 ONLY = barrier-free chain. 16 quads; quad t owns outputs
//   4t..4t+3 via 4 passes; lane (t,j) reads h[16j..16j+16) (4 b128), 16 fma
//   per pass, DPP quad_sum, tanh; j==0 packs {hn0..hn3} -> ONE b128 write to
//   hs[s+1][4t]. All h traffic same-wave in-order DS -> no __syncthreads.
//   pre staged per chunk into single LDS buffer; hs[65][64] rolls in place.
// blocks 1..1024 = state branch (mlp20 + final64 + cb, write out fully).
#define SMEMF_MAIN 14544   // floats; chain uses 8256, batch uses P_TOT

__global__ __launch_bounds__(256) void k_main(
    const float* __restrict__ t_in, const float* __restrict__ x_in,
    const float* __restrict__ i2h_w,
    const float* __restrict__ pre_i,
    const float* __restrict__ wp,
    float* __restrict__ hseq, float* __restrict__ out) {
    __shared__ float smem[SMEMF_MAIN];
    const int tid = threadIdx.x;
    const int bid = blockIdx.x;

    if (bid == 0) {
        if (tid >= 64) return;         // single wave; no barriers on this path
        float* pre = smem;             // [4096]
        float* hs  = smem + 4096;      // [65][64]: hs[s] = h BEFORE step s
        const int l = tid;
        const int t = l >> 2;          // quad index 0..15 (owns outputs 4t..4t+3)
        const int j = l & 3;           // slice index 0..3 (h[16j..16j+16))

        float wih[4][16];              // W[4t+p][16j+k], static-indexed
#pragma unroll
        for (int p = 0; p < 4; ++p)
#pragma unroll
            for (int k = 0; k < 16; ++k)
                wih[p][k] = i2h_w[(4 * t + p) * 72 + 8 + 16 * j + k];

        hs[l] = 0.0f;                  // h before step 0
        float4* h4w = reinterpret_cast<float4*>(hs);
        const float4* h4 = reinterpret_cast<const float4*>(hs);
        const float4* p4 = reinterpret_cast<const float4*>(pre);

        for (int c = 0; c < NCHUNK; ++c) {
            {   // stage pre chunk c (single buffer, 2 rounds of 8 f4/lane)
                const float4* pg = reinterpret_cast<const float4*>(pre_i + c * 4096);
                float4* pd = reinterpret_cast<float4*>(pre);
#pragma unroll
                for (int h8 = 0; h8 < 2; ++h8) {
                    float4 r0 = pg[(h8*8+0)*64 + l], r1 = pg[(h8*8+1)*64 + l];
                    float4 r2 = pg[(h8*8+2)*64 + l], r3 = pg[(h8*8+3)*64 + l];
                    float4 r4 = pg[(h8*8+4)*64 + l], r5 = pg[(h8*8+5)*64 + l];
                    float4 r6 = pg[(h8*8+6)*64 + l], r7 = pg[(h8*8+7)*64 + l];
                    pd[(h8*8+0)*64+l]=r0; pd[(h8*8+1)*64+l]=r1;
                    pd[(h8*8+2)*64+l]=r2; pd[(h8*8+3)*64+l]=r3;
                    pd[(h8*8+4)*64+l]=r4; pd[(h8*8+5)*64+l]=r5;
                    pd[(h8*8+6)*64+l]=r6; pd[(h8*8+7)*64+l]=r7;
                }
            }
            for (int s = 0; s < CHUNK; ++s) {
                float4 b0 = h4[s*16 + 4*j + 0];
                float4 b1 = h4[s*16 + 4*j + 1];
                float4 b2 = h4[s*16 + 4*j + 2];
                float4 b3 = h4[s*16 + 4*j + 3];
                float4 pr = p4[s*16 + t];        // pre for outputs 4t..4t+3
                float hn0, hn1, hn2, hn3;
                {
                    float a0 = wih[0][ 0]*b0.x + wih[0][ 1]*b0.y + wih[0][ 2]*b0.z + wih[0][ 3]*b0.w;
                    float a1 = wih[0][ 4]*b1.x + wih[0][ 5]*b1.y + wih[0][ 6]*b1.z + wih[0][ 7]*b1.w;
                    float a2 = wih[0][ 8]*b2.x + wih[0][ 9]*b2.y + wih[0][10]*b2.z + wih[0][11]*b2.w;
                    float a3 = wih[0][12]*b3.x + wih[0][13]*b3.y + wih[0][14]*b3.z + wih[0][15]*b3.w;
                    hn0 = fast_tanh(quad_sum((a0 + a1) + (a2 + a3)) + pr.x);
                }
                {
                    float a0 = wih[1][ 0]*b0.x + wih[1][ 1]*b0.y + wih[1][ 2]*b0.z + wih[1][ 3]*b0.w;
                    float a1 = wih[1][ 4]*b1.x + wih[1][ 5]*b1.y + wih[1][ 6]*b1.z + wih[1][ 7]*b1.w;
                    float a2 = wih[1][ 8]*b2.x + wih[1][ 9]*b2.y + wih[1][10]*b2.z + wih[1][11]*b2.w;
                    float a3 = wih[1][12]*b3.x + wih[1][13]*b3.y + wih[1][14]*b3.z + wih[1][15]*b3.w;
                    hn1 = fast_tanh(quad_sum((a0 + a1) + (a2 + a3)) + pr.y);
                }
                {
                    float a0 = wih[2][ 0]*b0.x + wih[2][ 1]*b0.y + wih[2][ 2]*b0.z + wih[2][ 3]*b0.w;
                    float a1 = wih[2][ 4]*b1.x + wih[2][ 5]*b1.y + wih[2][ 6]*b1.z + wih[2][ 7]*b1.w;
                    float a2 = wih[2][ 8]*b2.x + wih[2][ 9]*b2.y + wih[2][10]*b2.z + wih[2][11]*b2.w;
                    float a3 = wih[2][12]*b3.x + wih[2][13]*b3.y + wih[2][14]*b3.z + wih[2][15]*b3.w;
                    hn2 = fast_tanh(quad_sum((a0 + a1) + (a2 + a3)) + pr.z);
                }
                {
                    float a0 = wih[3][ 0]*b0.x + wih[3][ 1]*b0.y + wih[3][ 2]*b0.z + wih[3][ 3]*b0.w;
                    float a1 = wih[3][ 4]*b1.x + wih[3][ 5]*b1.y + wih[3][ 6]*b1.z + wih[3][ 7]*b1.w;
                    float a2 = wih[3][ 8]*b2.x + wih[3][ 9]*b2.y + wih[3][10]*b2.z + wih[3][11]*b2.w;
                    float a3 = wih[3][12]*b3.x + wih[3][13]*b3.y + wih[3][14]*b3.z + wih[3][15]*b3.w;
                    hn3 = fast_tanh(quad_sum((a0 + a1) + (a2 + a3)) + pr.w);
                }
                if (j == 0) {
                    float4 hv; hv.x = hn0; hv.y = hn1; hv.z = hn2; hv.w = hn3;
                    h4w[(s + 1) * 16 + t] = hv;   // outputs 4t..4t+3
                }
            }
            {   // flush hs rows 0..63 (h before steps of chunk c) to hseq
                float4* hdst = reinterpret_cast<float4*>(hseq + c * 4096);
#pragma unroll
                for (int q = 0; q < 16; ++q) hdst[q * 64 + l] = h4[q * 64 + l];
            }
            hs[l] = hs[4096 + l];      // carry hs[64] -> hs[0] (in-order after flush reads)
        }
        return;
    }

    // ---- state-branch blocks: full weight block, mlp20 + cb + final64, write out ----
    {
        float4* s4 = reinterpret_cast<float4*>(smem);
        const float4* w4 = reinterpret_cast<const float4*>(wp);
        for (int idx = tid; idx < P_TOT / 4; idx += 256) s4[idx] = w4[idx];
    }
    __syncthreads();

    const int r = (bid - 1) * 256 + tid;
    float tval = t_in[r];
    float4 z[16];
    const float4* xp = reinterpret_cast<const float4*>(x_in + (size_t)r * 64);
#pragma unroll
    for (int v = 0; v < 16; ++v) z[v] = xp[v];

    float h2[20];
    mlp20<P_SW1, P_SB1, P_SW2, P_SB2>(smem, tval, z, h2);

    float oacc[64];
    {
        const float4* cbp = reinterpret_cast<const float4*>(&smem[P_CB]);
#pragma unroll
        for (int v = 0; v < 16; ++v) {
            float4 c4 = cbp[v];
            oacc[4*v+0] = c4.x; oacc[4*v+1] = c4.y;
            oacc[4*v+2] = c4.z; oacc[4*v+3] = c4.w;
        }
    }
    final64<P_XW3, P_XB3, P_CWT>(smem, h2, oacc);

    float4* op = reinterpret_cast<float4*>(out + (size_t)r * 64);
#pragma unroll
    for (int v = 0; v < 16; ++v) {
        float4 f;
        f.x = oacc[4*v+0]; f.y = oacc[4*v+1];
        f.z = oacc[4*v+2]; f.w = oacc[4*v+3];
        op[v] = f;
    }
}

// ---- K_CTRL: ctrl mlp20 + final64-ctrl, accumulates into out (RMW) ----
__global__ __launch_bounds__(256) void k_ctrl(
    const float* __restrict__ t_in, const float* __restrict__ uo,
    const float* __restrict__ wp, float* __restrict__ out) {
    __shared__ float sm[P_TOT];
    const int tid = threadIdx.x;
    {
        float4* s4 = reinterpret_cast<float4*>(sm);
        const float4* w4 = reinterpret_cast<const float4*>(wp);
        for (int idx = tid; idx < P_TOT / 4; idx += 256) s4[idx] = w4[idx];
    }
    __syncthreads();

    const int r = blockIdx.x * 256 + tid;
    float tval = t_in[r];
    int ti = min((int)(tval * 1024.0f), 1023);
    float4 z[16];
    const float4* ep = reinterpret_cast<const float4*>(uo + ti * 64);
#pragma unroll
    for (int v = 0; v < 16; ++v) z[v] = ep[v];

    float h2[20];
    mlp20<P_UW1, P_UB1, P_UW2, P_UB2>(sm, tval, z, h2);

    float oacc[64];
    float4* op = reinterpret_cast<float4*>(out + (size_t)r * 64);
#pragma unroll
    for (int v = 0; v < 16; ++v) {
        float4 f = op[v];
        oacc[4*v+0] = f.x; oacc[4*v+1] = f.y;
        oacc[4*v+2] = f.z; oacc[4*v+3] = f.w;
    }
    final64<P_UW3, P_UB3, P_CWT + 64 * 64>(sm, h2, oacc);
#pragma unroll
    for (int v = 0; v < 16; ++v) {
        float4 f;
        f.x = oacc[4*v+0]; f.y = oacc[4*v+1];
        f.z = oacc[4*v+2]; f.w = oacc[4*v+3];
        op[v] = f;
    }
}

extern "C" void kernel_launch(void* const* d_in, const int* in_sizes, int n_in,
                              void* d_out, int out_size, void* d_ws, size_t ws_size,
                              hipStream_t stream) {
    const float* t     = (const float*)d_in[0];
    const float* x     = (const float*)d_in[1];
    const float* u     = (const float*)d_in[2];
    const float* i2h_w = (const float*)d_in[3];
    const float* i2h_b = (const float*)d_in[4];
    const float* h2o_w = (const float*)d_in[5];
    const float* h2o_b = (const float*)d_in[6];
    const float* xw1 = (const float*)d_in[7];  const float* xb1 = (const float*)d_in[8];
    const float* xw2 = (const float*)d_in[9];  const float* xb2 = (const float*)d_in[10];
    const float* xw3 = (const float*)d_in[11]; const float* xb3 = (const float*)d_in[12];
    const float* uw1 = (const float*)d_in[13]; const float* ub1 = (const float*)d_in[14];
    const float* uw2 = (const float*)d_in[15]; const float* ub2 = (const float*)d_in[16];
    const float* uw3 = (const float*)d_in[17]; const float* ub3 = (const float*)d_in[18];
    const float* cw  = (const float*)d_in[19]; const float* cb  = (const float*)d_in[20];
    float* out = (float*)d_out;

    float* ws = (float*)d_ws;
    // uo aliases pre_i (pre_i dead after k_main; uo written by k_rnn_out after)
    float* pre_i = ws;                 // [0,      65536)
    float* uo    = ws;                 //   alias, used post-k_main
    float* pre_o = ws + 65536;         // [65536, 131072)
    float* hseq  = ws + 131072;        // [131072,196608)
    float* wp    = ws + 196608;        // [196608,211152)

    int Bv = in_sizes[0];              // 262144

    hipLaunchKernelGGL(k_repack, dim3((P_TOT + 255) / 256), dim3(256), 0, stream,
                       xw1, uw1, xw2, uw2, xw3, uw3, cw,
                       xb1, xb2, ub1, ub2, xb3, ub3, cb, wp);
    hipLaunchKernelGGL(k_rnn_pre, dim3(256), dim3(256), 0, stream,
                       u, i2h_w, i2h_b, h2o_w, h2o_b, pre_i, pre_o);
    hipLaunchKernelGGL(k_main, dim3(1 + Bv / 256), dim3(256), 0, stream,
                       t, x, i2h_w, pre_i, wp, hseq, out);
    hipLaunchKernelGGL(k_rnn_out, dim3(T_SEQ / 4), dim3(256), 0, stream,
                       h2o_w, pre_o, hseq, uo);
    hipLaunchKernelGGL(k_ctrl, dim3(Bv / 256), dim3(256), 0, stream,
                       t, uo, wp, out);
}

// Round 17
// 312.516 us; speedup vs baseline: 1.6083x; 1.6083x over previous
//
#include <hip/hip_runtime.h>
#include <hip/hip_bf16.h>

#define T_SEQ 1024
#define CHUNK 64
#define NCHUNK 16

__device__ __forceinline__ float fast_sigmoid(float x) {
    return 1.0f / (1.0f + __expf(-x));
}
__device__ __forceinline__ float fast_tanh(float x) {
    float e = __expf(2.0f * x);
    return 1.0f - 2.0f / (e + 1.0f);
}

// sum within each 4-lane quad via DPP quad_perm (pure VALU, no LDS)
__device__ __forceinline__ float quad_sum(float x) {
    int y1 = __builtin_amdgcn_mov_dpp(__float_as_int(x), 0xB1, 0xF, 0xF, true); // [1,0,3,2]
    float s1 = x + __int_as_float(y1);
    int y2 = __builtin_amdgcn_mov_dpp(__float_as_int(s1), 0x4E, 0xF, 0xF, true); // [2,3,0,1]
    return s1 + __int_as_float(y2);
}

// ---- packed weight block layout (floats) ----
#define P_SW1 0       // xw1 padded rows of 68
#define P_SB1 1360
#define P_SW2 1380
#define P_SB2 1780
#define P_UW1 1800
#define P_UB1 3160
#define P_UW2 3180
#define P_UB2 3580
#define P_XW3 3600
#define P_XB3 4880
#define P_UW3 4944
#define P_UB3 6224
#define P_CWT 6288    // cwT[128][64]
#define P_CB  14480
#define P_TOT 14544   // 58176 bytes

// K_PREP: fused repack + rnn_pre.
// blocks 0..255: pre part -> pre_t[i*1024+k] (transposed, for in-register chain pre)
//                and pre_o[k*64+i] (for k_rnn_out).
// blocks 256..312: weight repack into wp.
__global__ __launch_bounds__(256) void k_prep(
    const float* __restrict__ u,
    const float* __restrict__ i2h_w, const float* __restrict__ i2h_b,
    const float* __restrict__ h2o_w, const float* __restrict__ h2o_b,
    const float* __restrict__ xw1, const float* __restrict__ uw1,
    const float* __restrict__ xw2, const float* __restrict__ uw2,
    const float* __restrict__ xw3, const float* __restrict__ uw3,
    const float* __restrict__ cw,
    const float* __restrict__ xb1, const float* __restrict__ xb2,
    const float* __restrict__ ub1, const float* __restrict__ ub2,
    const float* __restrict__ xb3, const float* __restrict__ ub3,
    const float* __restrict__ cb,
    float* __restrict__ pre_t, float* __restrict__ pre_o,
    float* __restrict__ wp) {
    const int bid = blockIdx.x, tid = threadIdx.x;
    if (bid < 256) {
        int idx = bid * 256 + tid;            // 0..65535
        int k = idx >> 6, i = idx & 63;
        float a = i2h_b[i], b = h2o_b[i];
#pragma unroll
        for (int c = 0; c < 8; ++c) {
            float uv = u[k * 8 + c];
            a += uv * i2h_w[i * 72 + c];
            b += uv * h2o_w[i * 72 + c];
        }
        pre_t[i * 1024 + k] = a;
        pre_o[idx] = b;
        return;
    }
    int i = (bid - 256) * 256 + tid;
    if (i >= P_TOT) return;
    float v = 0.0f;
    if (i < 1360) {
        int o = i / 68, c = i - o * 68;
        if (c == 0) v = xw1[o * 65];
        else if (c >= 4) v = xw1[o * 65 + c - 3];
    } else if (i < 1380) v = xb1[i - 1360];
    else if (i < 1780) v = xw2[i - 1380];
    else if (i < 1800) v = xb2[i - 1780];
    else if (i < 3160) {
        int j = i - 1800; int o = j / 68, c = j - o * 68;
        if (c == 0) v = uw1[o * 65];
        else if (c >= 4) v = uw1[o * 65 + c - 3];
    } else if (i < 3180) v = ub1[i - 3160];
    else if (i < 3580) v = uw2[i - 3180];
    else if (i < 3600) v = ub2[i - 3580];
    else if (i < 4880) v = xw3[i - 3600];
    else if (i < 4944) v = xb3[i - 4880];
    else if (i < 6224) v = uw3[i - 4944];
    else if (i < 6288) v = ub3[i - 6224];
    else if (i < 14480) {
        int j = i - 6288; int row = j >> 6, s = j & 63;
        v = cw[s * 128 + row];
    }
    else v = cb[i - 14480];
    wp[i] = v;
}

// K3: RNN outputs, 4 rows per 256-thread block (hseq[k] = h BEFORE step k)
__global__ __launch_bounds__(256) void k_rnn_out(
    const float* __restrict__ h2o_w,
    const float* __restrict__ pre_o,
    const float* __restrict__ hseq,
    float* __restrict__ uout) {
    const int tid = threadIdx.x;
    const int sub = tid >> 6, i = tid & 63;
    const int k = blockIdx.x * 4 + sub;
    __shared__ float hk[4][64];
    hk[sub][i] = hseq[k * 64 + i];
    __syncthreads();
    float acc = pre_o[k * 64 + i];
    const float4* h4 = reinterpret_cast<const float4*>(hk[sub]);
#pragma unroll
    for (int v = 0; v < 16; ++v) {
        float4 hv = h4[v];
        acc += h2o_w[i * 72 + 8 + 4*v+0] * hv.x + h2o_w[i * 72 + 8 + 4*v+1] * hv.y
             + h2o_w[i * 72 + 8 + 4*v+2] * hv.z + h2o_w[i * 72 + 8 + 4*v+3] * hv.w;
    }
    uout[k * 64 + i] = fast_tanh(acc);
}

// ---- MLP helpers (read LDS weight block) ----
template <int OW1, int OB1, int OW2, int OB2>
__device__ __forceinline__ void mlp20(const float* __restrict__ sm,
                                      float tval, const float4* z, float* h2) {
    float h1[20];
#pragma unroll 4
    for (int o = 0; o < 20; ++o) {
        const int ro = OW1 + o * 68;
        float a = sm[OB1 + o] + tval * sm[ro];
        const float4* wr = reinterpret_cast<const float4*>(&sm[ro + 4]);
#pragma unroll
        for (int v = 0; v < 16; ++v) {
            float4 w4 = wr[v];
            a += z[v].x * w4.x + z[v].y * w4.y + z[v].z * w4.z + z[v].w * w4.w;
        }
        h1[o] = fast_sigmoid(a);
    }
#pragma unroll 4
    for (int o = 0; o < 20; ++o) {
        float a = sm[OB2 + o];
        const float4* wr = reinterpret_cast<const float4*>(&sm[OW2 + o * 20]);
#pragma unroll
        for (int v = 0; v < 5; ++v) {
            float4 w4 = wr[v];
            a += h1[4*v+0]*w4.x + h1[4*v+1]*w4.y + h1[4*v+2]*w4.z + h1[4*v+3]*w4.w;
        }
        h2[o] = fast_sigmoid(a);
    }
}

template <int OW3, int OB3, int OCWT>
__device__ __forceinline__ void final64(const float* __restrict__ sm,
                                        const float* h2, float* oacc) {
#pragma unroll 2
    for (int o = 0; o < 64; ++o) {
        float a = sm[OB3 + o];
        const float4* wr = reinterpret_cast<const float4*>(&sm[OW3 + o * 20]);
#pragma unroll
        for (int v = 0; v < 5; ++v) {
            float4 w4 = wr[v];
            a += h2[4*v+0]*w4.x + h2[4*v+1]*w4.y + h2[4*v+2]*w4.z + h2[4*v+3]*w4.w;
        }
        float s = fast_sigmoid(a);
        const float4* cr = reinterpret_cast<const float4*>(&sm[OCWT + o * 64]);
#pragma unroll
        for (int v = 0; v < 16; ++v) {
            float4 c4 = cr[v];
            oacc[4*v+0] += s * c4.x; oacc[4*v+1] += s * c4.y;
            oacc[4*v+2] += s * c4.z; oacc[4*v+3] += s * c4.w;
        }
    }
}

// ---- K_MAIN ----
// block 0 = RNN chain (r14 DPP-quad, 4 waves, 1 barrier/step) with:
//   * setprio(3) (favor chain waves in SIMD issue arbitration vs batch mates)
//   * pre held in 64 REGISTERS per chunk (loaded from transposed pre_t),
//     inner 64-step loop fully unrolled so preg[s] is static (rule #20).
//   Chain DS/step = 4x ds_read_b128 + 1x ds_write_b32. hs[65][64] rolls.
// blocks 1..1024 = state branch (mlp20 + cb + final64-state, write out fully).
#define SMEMF_MAIN 14544   // floats; chain uses 4160+, batch uses P_TOT

__global__ __launch_bounds__(256) void k_main(
    const float* __restrict__ t_in, const float* __restrict__ x_in,
    const float* __restrict__ i2h_w,
    const float* __restrict__ pre_t,
    const float* __restrict__ wp,
    float* __restrict__ hseq, float* __restrict__ out) {
    __shared__ float smem[SMEMF_MAIN];
    const int tid = threadIdx.x;
    const int bid = blockIdx.x;

    if (bid == 0) {
        __builtin_amdgcn_s_setprio(3);
        float* hs = smem;              // [65][64]: hs[s] = h BEFORE step s
        const int lane = tid & 63;
        const int wv = tid >> 6;
        const int t = lane >> 2;       // output sub-index 0..15
        const int j = lane & 3;        // input-slice index 0..3
        const int o = 16 * wv + t;     // this lane's output index

        float wih[16];
#pragma unroll
        for (int jj = 0; jj < 16; ++jj) wih[jj] = i2h_w[o * 72 + 8 + 16 * jj / 16 * 0 + 16 * j + jj];
        // (the expression above simplifies to i2h_w[o*72+8+16*j+jj]; kept simple below)
#pragma unroll
        for (int jj = 0; jj < 16; ++jj) wih[jj] = i2h_w[o * 72 + 8 + 16 * j + jj];

        if (tid < 64) hs[tid] = 0.0f;  // h before step 0
        __syncthreads();
        const float4* h4 = reinterpret_cast<const float4*>(hs);

        for (int c = 0; c < NCHUNK; ++c) {
            // load this chunk's pre for output o into 64 registers (16 x b128)
            float preg[64];
            {
                const float4* pt = reinterpret_cast<const float4*>(pre_t + o * 1024 + c * 64);
#pragma unroll
                for (int q = 0; q < 16; ++q) {
                    float4 p = pt[q];
                    preg[4*q+0] = p.x; preg[4*q+1] = p.y;
                    preg[4*q+2] = p.z; preg[4*q+3] = p.w;
                }
            }
#pragma unroll
            for (int s = 0; s < CHUNK; ++s) {
                const float4* hb = h4 + s * 16 + 4 * j;
                float4 b0 = hb[0], b1 = hb[1], b2 = hb[2], b3 = hb[3];
                float a0 = wih[ 0]*b0.x + wih[ 1]*b0.y + wih[ 2]*b0.z + wih[ 3]*b0.w;
                float a1 = wih[ 4]*b1.x + wih[ 5]*b1.y + wih[ 6]*b1.z + wih[ 7]*b1.w;
                float a2 = wih[ 8]*b2.x + wih[ 9]*b2.y + wih[10]*b2.z + wih[11]*b2.w;
                float a3 = wih[12]*b3.x + wih[13]*b3.y + wih[14]*b3.z + wih[15]*b3.w;
                float tot = quad_sum((a0 + a1) + (a2 + a3));
                float hn = fast_tanh(tot + preg[s]);
                if (j == 0) hs[(s + 1) * 64 + o] = hn;
                __syncthreads();
            }
            {   // flush hs rows 0..63 (h before this chunk's steps) to hseq
                const float4* hsrc = reinterpret_cast<const float4*>(hs);
                float4* hdst = reinterpret_cast<float4*>(hseq + c * 4096);
#pragma unroll
                for (int q = 0; q < 4; ++q) hdst[tid * 4 + q] = hsrc[tid * 4 + q];
            }
            __syncthreads();           // flush reads complete before carry overwrites
            if (tid < 64) hs[tid] = hs[4096 + tid];   // carry: hs[64] -> hs[0]
            __syncthreads();
        }
        return;
    }

    // ---- state-branch blocks: full weight block, mlp20 + cb + final64, write out ----
    {
        float4* s4 = reinterpret_cast<float4*>(smem);
        const float4* w4 = reinterpret_cast<const float4*>(wp);
        for (int idx = tid; idx < P_TOT / 4; idx += 256) s4[idx] = w4[idx];
    }
    __syncthreads();

    const int r = (bid - 1) * 256 + tid;
    float tval = t_in[r];
    float4 z[16];
    const float4* xp = reinterpret_cast<const float4*>(x_in + (size_t)r * 64);
#pragma unroll
    for (int v = 0; v < 16; ++v) z[v] = xp[v];

    float h2[20];
    mlp20<P_SW1, P_SB1, P_SW2, P_SB2>(smem, tval, z, h2);

    float oacc[64];
    {
        const float4* cbp = reinterpret_cast<const float4*>(&smem[P_CB]);
#pragma unroll
        for (int v = 0; v < 16; ++v) {
            float4 c4 = cbp[v];
            oacc[4*v+0] = c4.x; oacc[4*v+1] = c4.y;
            oacc[4*v+2] = c4.z; oacc[4*v+3] = c4.w;
        }
    }
    final64<P_XW3, P_XB3, P_CWT>(smem, h2, oacc);

    float4* op = reinterpret_cast<float4*>(out + (size_t)r * 64);
#pragma unroll
    for (int v = 0; v < 16; ++v) {
        float4 f;
        f.x = oacc[4*v+0]; f.y = oacc[4*v+1];
        f.z = oacc[4*v+2]; f.w = oacc[4*v+3];
        op[v] = f;
    }
}

// ---- K_CTRL: ctrl mlp20 + final64-ctrl, accumulates into out (RMW) ----
__global__ __launch_bounds__(256) void k_ctrl(
    const float* __restrict__ t_in, const float* __restrict__ uo,
    const float* __restrict__ wp, float* __restrict__ out) {
    __shared__ float sm[P_TOT];
    const int tid = threadIdx.x;
    {
        float4* s4 = reinterpret_cast<float4*>(sm);
        const float4* w4 = reinterpret_cast<const float4*>(wp);
        for (int idx = tid; idx < P_TOT / 4; idx += 256) s4[idx] = w4[idx];
    }
    __syncthreads();

    const int r = blockIdx.x * 256 + tid;
    float tval = t_in[r];
    int ti = min((int)(tval * 1024.0f), 1023);
    float4 z[16];
    const float4* ep = reinterpret_cast<const float4*>(uo + ti * 64);
#pragma unroll
    for (int v = 0; v < 16; ++v) z[v] = ep[v];

    float h2[20];
    mlp20<P_UW1, P_UB1, P_UW2, P_UB2>(sm, tval, z, h2);

    float oacc[64];
    float4* op = reinterpret_cast<float4*>(out + (size_t)r * 64);
#pragma unroll
    for (int v = 0; v < 16; ++v) {
        float4 f = op[v];
        oacc[4*v+0] = f.x; oacc[4*v+1] = f.y;
        oacc[4*v+2] = f.z; oacc[4*v+3] = f.w;
    }
    final64<P_UW3, P_UB3, P_CWT + 64 * 64>(sm, h2, oacc);
#pragma unroll
    for (int v = 0; v < 16; ++v) {
        float4 f;
        f.x = oacc[4*v+0]; f.y = oacc[4*v+1];
        f.z = oacc[4*v+2]; f.w = oacc[4*v+3];
        op[v] = f;
    }
}

extern "C" void kernel_launch(void* const* d_in, const int* in_sizes, int n_in,
                              void* d_out, int out_size, void* d_ws, size_t ws_size,
                              hipStream_t stream) {
    const float* t     = (const float*)d_in[0];
    const float* x     = (const float*)d_in[1];
    const float* u     = (const float*)d_in[2];
    const float* i2h_w = (const float*)d_in[3];
    const float* i2h_b = (const float*)d_in[4];
    const float* h2o_w = (const float*)d_in[5];
    const float* h2o_b = (const float*)d_in[6];
    const float* xw1 = (const float*)d_in[7];  const float* xb1 = (const float*)d_in[8];
    const float* xw2 = (const float*)d_in[9];  const float* xb2 = (const float*)d_in[10];
    const float* xw3 = (const float*)d_in[11]; const float* xb3 = (const float*)d_in[12];
    const float* uw1 = (const float*)d_in[13]; const float* ub1 = (const float*)d_in[14];
    const float* uw2 = (const float*)d_in[15]; const float* ub2 = (const float*)d_in[16];
    const float* uw3 = (const float*)d_in[17]; const float* ub3 = (const float*)d_in[18];
    const float* cw  = (const float*)d_in[19]; const float* cb  = (const float*)d_in[20];
    float* out = (float*)d_out;

    float* ws = (float*)d_ws;
    // uo aliases pre_t (pre_t dead after k_main; uo written by k_rnn_out after)
    float* pre_t = ws;                 // [0,      65536)  transposed pre
    float* uo    = ws;                 //   alias, used post-k_main
    float* pre_o = ws + 65536;         // [65536, 131072)
    float* hseq  = ws + 131072;        // [131072,196608)
    float* wp    = ws + 196608;        // [196608,211152)

    int Bv = in_sizes[0];              // 262144

    hipLaunchKernelGGL(k_prep, dim3(256 + (P_TOT + 255) / 256), dim3(256), 0, stream,
                       u, i2h_w, i2h_b, h2o_w, h2o_b,
                       xw1, uw1, xw2, uw2, xw3, uw3, cw,
                       xb1, xb2, ub1, ub2, xb3, ub3, cb,
                       pre_t, pre_o, wp);
    hipLaunchKernelGGL(k_main, dim3(1 + Bv / 256), dim3(256), 0, stream,
                       t, x, i2h_w, pre_t, wp, hseq, out);
    hipLaunchKernelGGL(k_rnn_out, dim3(T_SEQ / 4), dim3(256), 0, stream,
                       h2o_w, pre_o, hseq, uo);
    hipLaunchKernelGGL(k_ctrl, dim3(Bv / 256), dim3(256), 0, stream,
                       t, uo, wp, out);
}